// Round 15
// baseline (163.572 us; speedup 1.0000x reference)
//
#include <hip/hip_runtime.h>
#include <hip/hip_bf16.h>
#include <cstdint>

#define DIMSZ 1024
#define S_LEN 2048
#define NH 16
#define HD 64

typedef __attribute__((ext_vector_type(4))) float f32x4;
typedef __attribute__((ext_vector_type(8))) __bf16 bf16x8;

#define MFMA_BF16(a,b,c) __builtin_amdgcn_mfma_f32_16x16x32_bf16((a),(b),(c),0,0,0)

__device__ __forceinline__ void gload_lds16(const void* g, void* l) {
  __builtin_amdgcn_global_load_lds(
      (const __attribute__((address_space(1))) unsigned int*)(uintptr_t)g,
      (__attribute__((address_space(3))) unsigned int*)(uintptr_t)l,
      16, 0, 0);
}

__device__ __forceinline__ float bf16bits2f(unsigned short u) {
  return __uint_as_float((unsigned)u << 16);
}

// single-op packed f32x2 -> bf16x2
__device__ __forceinline__ unsigned cvt_pk_bf16(float lo, float hi) {
  unsigned r;
  asm("v_cvt_pk_bf16_f32 %0, %1, %2" : "=v"(r) : "v"(lo), "v"(hi));
  return r;
}

// ---------------- prep: wq cast (blocks 0..3071) + pre-attn RMSNorm (3072..7167) ----
__global__ __launch_bounds__(256)
void prep_kernel(const float* __restrict__ wq_f, __hip_bfloat16* __restrict__ wq_b,
                 const float* __restrict__ x, const float* __restrict__ w_in,
                 __hip_bfloat16* __restrict__ h)
{
  __shared__ float red[4];
  const int bid = blockIdx.x;
  const int tid = threadIdx.x;
  if (bid < 3072) {
    int off = bid * 256 + tid;   // float4 index, total 786432
    float4 v = ((const float4*)wq_f)[off];
    __hip_bfloat16* o = wq_b + (size_t)off * 4;
    o[0] = __float2bfloat16(v.x);
    o[1] = __float2bfloat16(v.y);
    o[2] = __float2bfloat16(v.z);
    o[3] = __float2bfloat16(v.w);
    return;
  }
  const int row = bid - 3072;
  const float4 v = ((const float4*)(x + (size_t)row * DIMSZ))[tid];
  float ss = v.x*v.x + v.y*v.y + v.z*v.z + v.w*v.w;
  #pragma unroll
  for (int m = 32; m >= 1; m >>= 1) ss += __shfl_xor(ss, m);
  int wave = tid >> 6, lane = tid & 63;
  if (lane == 0) red[wave] = ss;
  __syncthreads();
  float tot = red[0] + red[1] + red[2] + red[3];
  float sc = rsqrtf(tot * (1.0f / DIMSZ) + 1e-6f);
  const float4 wv = ((const float4*)w_in)[tid];
  __hip_bfloat16* o = h + (size_t)row * DIMSZ + tid * 4;
  o[0] = __float2bfloat16(v.x * sc * wv.x);
  o[1] = __float2bfloat16(v.y * sc * wv.y);
  o[2] = __float2bfloat16(v.z * sc * wv.z);
  o[3] = __float2bfloat16(v.w * sc * wv.w);
}

// ---------------- RMSNorm over bf16 input (residual stream) -> bf16 out ----------------
__global__ __launch_bounds__(256)
void rmsnorm_bf16_kernel(const __hip_bfloat16* __restrict__ x, const float* __restrict__ w,
                         __hip_bfloat16* __restrict__ out)
{
  int row = blockIdx.x;
  int tid = threadIdx.x;
  const ushort4 raw = ((const ushort4*)(x + (size_t)row * DIMSZ))[tid];
  float v0 = bf16bits2f(raw.x), v1 = bf16bits2f(raw.y);
  float v2 = bf16bits2f(raw.z), v3 = bf16bits2f(raw.w);
  float ss = v0*v0 + v1*v1 + v2*v2 + v3*v3;
  #pragma unroll
  for (int m = 32; m >= 1; m >>= 1) ss += __shfl_xor(ss, m);
  __shared__ float red[4];
  int wave = tid >> 6, lane = tid & 63;
  if (lane == 0) red[wave] = ss;
  __syncthreads();
  float tot = red[0] + red[1] + red[2] + red[3];
  float sc = rsqrtf(tot * (1.0f / DIMSZ) + 1e-6f);
  const float4 wv = ((const float4*)w)[tid];
  __hip_bfloat16* o = out + (size_t)row * DIMSZ + tid * 4;
  o[0] = __float2bfloat16(v0 * sc * wv.x);
  o[1] = __float2bfloat16(v1 * sc * wv.y);
  o[2] = __float2bfloat16(v2 * sc * wv.z);
  o[3] = __float2bfloat16(v3 * sc * wv.w);
}

// ---------------- GEMM v2: 128x128 2-phase, BK=64, dbuf, swizzled (verified) ---
// EPI 0: bf16 raw; EPI 1: bf16(residf + acc); EPI 2: bf16 silu(acc);
// EPI 3: fp32 (residb + acc).
template<int EPI>
__global__ __launch_bounds__(256, 2)
void gemm_bt2(const __hip_bfloat16* __restrict__ A,
              const __hip_bfloat16* __restrict__ Bw,
              float* __restrict__ Cf,
              __hip_bfloat16* __restrict__ Cb,
              const float* __restrict__ residf,
              const __hip_bfloat16* __restrict__ residb,
              int N, int K)
{
  __shared__ __align__(16) char sA[2][16384];   // [128 rows][128 B]
  __shared__ __align__(16) char sB[2][16384];
  const int tid = threadIdx.x;
  const int wave = tid >> 6, lane = tid & 63;
  const int lg = lane >> 4, lr15 = lane & 15;
  const int row0 = blockIdx.y * 128, col0 = blockIdx.x * 128;
  const int wr = wave >> 1, wc = wave & 1;
  f32x4 acc[4][4] = {};

  const size_t Kb = (size_t)K * 2;
  const int rown = tid >> 3;               // 0..31
  const int scol = ((tid & 7) << 4) ^ ((rown & 7) << 4);
  const char* gA = (const char*)A + (size_t)(row0 + rown) * Kb + scol;
  const char* gB = (const char*)Bw + (size_t)(col0 + rown) * Kb + scol;
  const int dbase = wave * 1024;

  const int nsteps = K >> 6;
  int cur = 0;

#define STAGE_G(buf, st) do {                                              \
    const size_t kb_ = (size_t)(st) * 128;                                 \
    _Pragma("unroll")                                                      \
    for (int it = 0; it < 4; ++it) {                                       \
      gload_lds16(gA + (size_t)(it * 32) * Kb + kb_, &sA[buf][it * 4096 + dbase]); \
      gload_lds16(gB + (size_t)(it * 32) * Kb + kb_, &sB[buf][it * 4096 + dbase]); \
    }                                                                      \
  } while (0)

  STAGE_G(0, 0);
  __syncthreads();

  const int swz = (lr15 & 7) << 4;
  for (int st = 0; st < nsteps; ++st) {
    if (st + 1 < nsteps) STAGE_G(cur ^ 1, st + 1);
    const char* pA = sA[cur];
    const char* pB = sB[cur];
    bf16x8 af[2][4], bfr[2][4];
    #pragma unroll
    for (int m = 0; m < 4; ++m) {
      const int ra = (wr * 64 + m * 16 + lr15) * 128;
      af[0][m] = *(const bf16x8*)(pA + ra + ((lg * 16) ^ swz));
      af[1][m] = *(const bf16x8*)(pA + ra + ((64 + lg * 16) ^ swz));
      const int rb = (wc * 64 + m * 16 + lr15) * 128;
      bfr[0][m] = *(const bf16x8*)(pB + rb + ((lg * 16) ^ swz));
      bfr[1][m] = *(const bf16x8*)(pB + rb + ((64 + lg * 16) ^ swz));
    }
    #pragma unroll
    for (int kh = 0; kh < 2; ++kh)
      #pragma unroll
      for (int m = 0; m < 4; ++m)
        #pragma unroll
        for (int n = 0; n < 4; ++n)
          acc[m][n] = MFMA_BF16(af[kh][m], bfr[kh][n], acc[m][n]);
    __syncthreads();
    cur ^= 1;
  }
#undef STAGE_G

  #pragma unroll
  for (int m = 0; m < 4; ++m) {
    #pragma unroll
    for (int n = 0; n < 4; ++n) {
      #pragma unroll
      for (int r = 0; r < 4; ++r) {
        const int grow = row0 + wr * 64 + m * 16 + lg * 4 + r;
        const int gcol = col0 + wc * 64 + n * 16 + lr15;
        const size_t idx = (size_t)grow * N + gcol;
        const float v = acc[m][n][r];
        if (EPI == 0) {
          Cb[idx] = __float2bfloat16(v);
        } else if (EPI == 1) {
          Cb[idx] = __float2bfloat16(residf[idx] + v);
        } else if (EPI == 2) {
          Cb[idx] = __float2bfloat16(v / (1.0f + __expf(-v)));
        } else {
          Cf[idx] = __bfloat162float(residb[idx]) + v;
        }
      }
    }
  }
}

// ---------------- GEMM BN=192: 128x192 tile, 6 waves (2x3), 2-phase, 80 KB LDS ------
// For QKV (N=3072): BM=128/BN=128 gives 768 blocks at 2/CU capacity (512) -> 75%
// shape utilization. BN=192 -> grid exactly 512 = one full dispatch round, and
// per-wave math is BYTE-IDENTICAL to gemm_bt2 (64x64 tile, acc[4][4], 32
// MFMA/step/wave) so per-block efficiency is preserved (unlike BM=64, r14).
// Staging: 40 wave-issue slots/step (8 rows x 128 B each; A=0..15, B=16..39)
// over 6 waves x 7 issues, wave-uniform skip for slots >= 40.
__global__ __launch_bounds__(384, 3)
void gemm_bt192(const __hip_bfloat16* __restrict__ A,
                const __hip_bfloat16* __restrict__ Bw,
                __hip_bfloat16* __restrict__ Cb,
                int N, int K)
{
  __shared__ __align__(16) char sA[2][16384];   // [128 rows][128 B]
  __shared__ __align__(16) char sB[2][24576];   // [192 rows][128 B]
  const int tid = threadIdx.x;
  const int wave = tid >> 6, lane = tid & 63;
  const int lg = lane >> 4, lr15 = lane & 15;
  const int row0 = blockIdx.y * 128, col0 = blockIdx.x * 192;
  const int wr = wave / 3, wc = wave % 3;       // 2 x 3 wave grid
  f32x4 acc[4][4] = {};

  const size_t Kb = (size_t)K * 2;
  const int lrow = lane >> 3;                   // 0..7 (row within 8-row slot)
  const int scol0 = (lane & 7) << 4;            // 0..112 (16B col)

  const int nsteps = K >> 6;
  int cur = 0;

  // stage: for issue i, slot = i*6 + wave (skip >= 40). slot<16 -> A rows slot*8;
  // else B rows (slot-16)*8. LDS dest = base + slot_local*1024 (linear, lane-ordered).
#define STAGE_192(buf, st) do {                                                     \
    const size_t kb_ = (size_t)(st) * 128;                                          \
    _Pragma("unroll")                                                               \
    for (int i = 0; i < 7; ++i) {                                                   \
      const int slot = i * 6 + wave;                                                \
      if (slot < 40) {                                                              \
        const bool isA = slot < 16;                                                 \
        const int r8 = (isA ? slot : slot - 16) * 8 + lrow;                         \
        const int sc = scol0 ^ ((r8 & 7) << 4);                                     \
        const char* src = (isA ? (const char*)A + (size_t)(row0 + r8) * Kb          \
                               : (const char*)Bw + (size_t)(col0 + r8) * Kb) + sc + kb_; \
        char* dst = (isA ? &sA[buf][slot * 1024] : &sB[buf][(slot - 16) * 1024]);   \
        gload_lds16(src, dst);                                                      \
      }                                                                             \
    }                                                                               \
  } while (0)

  STAGE_192(0, 0);
  __syncthreads();

  const int swz = (lr15 & 7) << 4;
  for (int st = 0; st < nsteps; ++st) {
    if (st + 1 < nsteps) STAGE_192(cur ^ 1, st + 1);
    const char* pA = sA[cur];
    const char* pB = sB[cur];
    bf16x8 af[2][4], bfr[2][4];
    #pragma unroll
    for (int m = 0; m < 4; ++m) {
      const int ra = (wr * 64 + m * 16 + lr15) * 128;
      af[0][m] = *(const bf16x8*)(pA + ra + ((lg * 16) ^ swz));
      af[1][m] = *(const bf16x8*)(pA + ra + ((64 + lg * 16) ^ swz));
      const int rb = (wc * 64 + m * 16 + lr15) * 128;
      bfr[0][m] = *(const bf16x8*)(pB + rb + ((lg * 16) ^ swz));
      bfr[1][m] = *(const bf16x8*)(pB + rb + ((64 + lg * 16) ^ swz));
    }
    #pragma unroll
    for (int kh = 0; kh < 2; ++kh)
      #pragma unroll
      for (int m = 0; m < 4; ++m)
        #pragma unroll
        for (int n = 0; n < 4; ++n)
          acc[m][n] = MFMA_BF16(af[kh][m], bfr[kh][n], acc[m][n]);
    __syncthreads();
    cur ^= 1;
  }
#undef STAGE_192

  #pragma unroll
  for (int m = 0; m < 4; ++m) {
    #pragma unroll
    for (int n = 0; n < 4; ++n) {
      #pragma unroll
      for (int r = 0; r < 4; ++r) {
        const int grow = row0 + wr * 64 + m * 16 + lg * 4 + r;
        const int gcol = col0 + wc * 64 + n * 16 + lr15;
        Cb[(size_t)grow * N + gcol] = __float2bfloat16(acc[m][n][r]);
      }
    }
  }
}

// ---------------- GEMM BM=64: 64x128 tile, 2-phase, 48 KB LDS, 3 blocks/CU ----------
template<int EPI>
__global__ __launch_bounds__(256, 3)
void gemm_bt64(const __hip_bfloat16* __restrict__ A,
               const __hip_bfloat16* __restrict__ Bw,
               float* __restrict__ Cf,
               __hip_bfloat16* __restrict__ Cb,
               const float* __restrict__ residf,
               const __hip_bfloat16* __restrict__ residb,
               int N, int K)
{
  __shared__ __align__(16) char sA[2][8192];    // [64 rows][128 B]
  __shared__ __align__(16) char sB[2][16384];   // [128 rows][128 B]
  const int tid = threadIdx.x;
  const int wave = tid >> 6, lane = tid & 63;
  const int lg = lane >> 4, lr15 = lane & 15;
  const int row0 = blockIdx.y * 64, col0 = blockIdx.x * 128;
  const int wr = wave >> 1, wc = wave & 1;
  f32x4 acc[2][4] = {};

  const size_t Kb = (size_t)K * 2;
  const int rown = tid >> 3;               // 0..31
  const int scol = ((tid & 7) << 4) ^ ((rown & 7) << 4);
  const char* gA = (const char*)A + (size_t)(row0 + rown) * Kb + scol;
  const char* gB = (const char*)Bw + (size_t)(col0 + rown) * Kb + scol;
  const int dbase = wave * 1024;

  const int nsteps = K >> 6;
  int cur = 0;

#define STAGE_G64(buf, st) do {                                            \
    const size_t kb_ = (size_t)(st) * 128;                                 \
    _Pragma("unroll")                                                      \
    for (int it = 0; it < 2; ++it)                                         \
      gload_lds16(gA + (size_t)(it * 32) * Kb + kb_, &sA[buf][it * 4096 + dbase]); \
    _Pragma("unroll")                                                      \
    for (int it = 0; it < 4; ++it)                                         \
      gload_lds16(gB + (size_t)(it * 32) * Kb + kb_, &sB[buf][it * 4096 + dbase]); \
  } while (0)

  STAGE_G64(0, 0);
  __syncthreads();

  const int swz = (lr15 & 7) << 4;
  for (int st = 0; st < nsteps; ++st) {
    if (st + 1 < nsteps) STAGE_G64(cur ^ 1, st + 1);
    const char* pA = sA[cur];
    const char* pB = sB[cur];
    bf16x8 af[2][2], bfr[2][4];
    #pragma unroll
    for (int m = 0; m < 2; ++m) {
      const int ra = (wr * 32 + m * 16 + lr15) * 128;
      af[0][m] = *(const bf16x8*)(pA + ra + ((lg * 16) ^ swz));
      af[1][m] = *(const bf16x8*)(pA + ra + ((64 + lg * 16) ^ swz));
    }
    #pragma unroll
    for (int n = 0; n < 4; ++n) {
      const int rb = (wc * 64 + n * 16 + lr15) * 128;
      bfr[0][n] = *(const bf16x8*)(pB + rb + ((lg * 16) ^ swz));
      bfr[1][n] = *(const bf16x8*)(pB + rb + ((64 + lg * 16) ^ swz));
    }
    #pragma unroll
    for (int kh = 0; kh < 2; ++kh)
      #pragma unroll
      for (int m = 0; m < 2; ++m)
        #pragma unroll
        for (int n = 0; n < 4; ++n)
          acc[m][n] = MFMA_BF16(af[kh][m], bfr[kh][n], acc[m][n]);
    __syncthreads();
    cur ^= 1;
  }
#undef STAGE_G64

  #pragma unroll
  for (int m = 0; m < 2; ++m) {
    #pragma unroll
    for (int n = 0; n < 4; ++n) {
      #pragma unroll
      for (int r = 0; r < 4; ++r) {
        const int grow = row0 + wr * 32 + m * 16 + lg * 4 + r;
        const int gcol = col0 + wc * 64 + n * 16 + lr15;
        const size_t idx = (size_t)grow * N + gcol;
        const float v = acc[m][n][r];
        if (EPI == 1) {
          Cb[idx] = __float2bfloat16(residf[idx] + v);
        } else {
          Cf[idx] = __bfloat162float(residb[idx]) + v;
        }
      }
    }
  }
}

// ---------------- fused RoPE (blocks 0..8191) + V transpose (8192..9215) ----------
__global__ __launch_bounds__(256)
void rope_vt_kernel(const __hip_bfloat16* __restrict__ qkv,
                    __hip_bfloat16* __restrict__ Q, __hip_bfloat16* __restrict__ Kx,
                    __hip_bfloat16* __restrict__ Vt)
{
  __shared__ __hip_bfloat16 t[64][72];
  const int bid = blockIdx.x;
  const int tid = threadIdx.x;
  if (bid < 8192) {
    int idx = bid * 256 + tid;   // bits: i:5, h:4, s:11, b:1
    int i = idx & 31;
    int h = (idx >> 5) & 15;
    int s = (idx >> 9) & (S_LEN - 1);
    int b = idx >> 20;
    const size_t base = ((size_t)b * S_LEN + s) * 3072 + h * 64 + 2 * i;
    float qe = __bfloat162float(qkv[base]);
    float qo = __bfloat162float(qkv[base + 1]);
    float ke = __bfloat162float(qkv[base + 1024]);
    float ko = __bfloat162float(qkv[base + 1025]);
    float inv = __expf(-(2.0f * i) * (9.210340371976184f / 64.0f));
    float ang = (float)s * inv;
    float sn, cs;
    __sincosf(ang, &sn, &cs);
    const float sc = 0.125f;   // 1/sqrt(HD) folded into Q
    size_t qb = (((size_t)b * NH + h) * S_LEN + s) * HD + 2 * i;
    Q[qb]     = __float2bfloat16((qe * cs - qo * sn) * sc);
    Q[qb + 1] = __float2bfloat16((qo * cs + qe * sn) * sc);
    Kx[qb]     = __float2bfloat16(ke * cs - ko * sn);
    Kx[qb + 1] = __float2bfloat16(ko * cs + ke * sn);
    return;
  }
  const int v = bid - 8192;          // 0..1023
  const int bh = v >> 5;
  const int s0 = (v & 31) * 64;
  const int b = bh >> 4, h = bh & 15;
  const int c = tid & 63;
  #pragma unroll
  for (int r = 0; r < 16; ++r) {
    int srow = r * 4 + (tid >> 6);
    t[srow][c] = qkv[((size_t)b * S_LEN + s0 + srow) * 3072 + 2048 + h * 64 + c];
  }
  __syncthreads();
  #pragma unroll
  for (int r = 0; r < 16; ++r) {
    int drow = r * 4 + (tid >> 6);
    Vt[(((size_t)b * NH + h) * HD + drow) * S_LEN + s0 + c] = t[c][drow];
  }
}

// ---------------- flash attention v7 (round-10 verified, 42.3 us) ----------------
__global__ __launch_bounds__(512, 4)
void flash_attn7(const __hip_bfloat16* __restrict__ Q,
                 const __hip_bfloat16* __restrict__ Kx,
                 const __hip_bfloat16* __restrict__ Vt,
                 __hip_bfloat16* __restrict__ attn,
                 const float* __restrict__ wo_f, const float* __restrict__ wfc_f,
                 const float* __restrict__ wpr_f,
                 __hip_bfloat16* __restrict__ wo_b, __hip_bfloat16* __restrict__ wfc_b,
                 __hip_bfloat16* __restrict__ wpr_b)
{
  __shared__ __align__(16) char sK[2][8192];
  __shared__ __align__(16) char sV[2][8192];
  __shared__ __align__(16) char sP[8][2048];

  const int tid = threadIdx.x;
  const int w = tid >> 6;           // wave 0..7
  const int lane = tid & 63;
  const int lg = lane >> 4, lr = lane & 15;
  const int bid = blockIdx.x;
  const int bh = bid & 31;          // b*16+h
  const int b = bh >> 4, h = bh & 15;
  const int u = (bid >> 5) & 7;     // slot within dispatch round
  const int rnd = bid >> 8;         // 0 or 1
  const int qb = rnd == 0 ? (u << 1) : (15 - (u << 1));   // {0,2,..14} then {15,13,..1}
  const int q0 = qb << 7;           // *128
  const int nsteps = (qb << 1) + 2;

  const char* Kb = (const char*)(Kx + (size_t)bh * S_LEN * HD);   // [S][64] bf16
  const char* Vb = (const char*)(Vt + (size_t)bh * HD * S_LEN);   // [64][S] bf16
  const __hip_bfloat16* Qp = Q + (size_t)bh * S_LEN * HD;

  const int q0w = q0 + w * 16;
  const bf16x8 qf0 = *(const bf16x8*)&Qp[(q0w + lr) * HD + lg * 8];
  const bf16x8 qf1 = *(const bf16x8*)&Qp[(q0w + lr) * HD + 32 + lg * 8];
  char* sPw = sP[w];
  const int swzr = (lr & 7) << 4;
  const int srow = tid >> 3;
  const int scol = ((tid & 7) << 4) ^ ((srow & 7) << 4);
  const int wbase = w << 10;        // wave-uniform LDS chunk

  bf16x8 ones;
  #pragma unroll
  for (int i = 0; i < 8; ++i) ones[i] = (__bf16)1.0f;

  f32x4 acc[4] = {};
  f32x4 acc_l = {};                 // rowsum of P (denominator)
  int cur = 0;

  gload_lds16(Kb + (size_t)srow * 128 + scol, sK[0] + wbase);
  gload_lds16(Vb + (size_t)srow * (S_LEN * 2) + scol, sV[0] + wbase);
  __syncthreads();

  for (int st = 0; st < nsteps; ++st) {
    if (st + 1 < nsteps) {
      const size_t kn = (size_t)(st + 1) * 64;
      gload_lds16(Kb + (kn + srow) * 128 + scol, sK[cur ^ 1] + wbase);
      gload_lds16(Vb + (size_t)srow * (S_LEN * 2) + kn * 2 + scol, sV[cur ^ 1] + wbase);
    }
    const int k0 = st * 64;
    const char* pK = sK[cur];
    const char* pV = sV[cur];
    f32x4 sv[4];
    __builtin_amdgcn_s_setprio(1);
    #pragma unroll
    for (int t = 0; t < 4; ++t) {
      const int rb = (t * 16 + lr) * 128;
      const bf16x8 kf0 = *(const bf16x8*)(pK + rb + ((lg * 16) ^ swzr));
      const bf16x8 kf1 = *(const bf16x8*)(pK + rb + ((64 + lg * 16) ^ swzr));
      f32x4 z = {};
      z = MFMA_BF16(kf0, qf0, z);
      z = MFMA_BF16(kf1, qf1, z);
      sv[t] = z;
    }
    __builtin_amdgcn_s_setprio(0);
    const bool maskstep = (st >= nsteps - 2);   // last two steps cross the diagonal
    #pragma unroll
    for (int t = 0; t < 4; ++t) {
      float p[4];
      #pragma unroll
      for (int r = 0; r < 4; ++r) {
        float e = __expf(sv[t][r]);
        if (maskstep) {
          const int kg = k0 + t * 16 + lg * 4 + r;
          e = (kg <= q0w + lr) ? e : 0.f;
        }
        p[r] = e;
      }
      uint2 wv2;
      wv2.x = cvt_pk_bf16(p[0], p[1]);
      wv2.y = cvt_pk_bf16(p[2], p[3]);
      *(uint2*)(sPw + lr * 128 + ((t * 32 + lg * 8) ^ swzr)) = wv2;
    }
    asm volatile("s_waitcnt lgkmcnt(0)" ::: "memory");
    __builtin_amdgcn_sched_barrier(0);
    const bf16x8 pa0 = *(const bf16x8*)(sPw + lr * 128 + ((lg * 16) ^ swzr));
    const bf16x8 pa1 = *(const bf16x8*)(sPw + lr * 128 + ((64 + lg * 16) ^ swzr));
    __builtin_amdgcn_s_setprio(1);
    #pragma unroll
    for (int dt = 0; dt < 4; ++dt) {
      const int rb = (dt * 16 + lr) * 128;
      const bf16x8 vf0 = *(const bf16x8*)(pV + rb + ((lg * 16) ^ swzr));
      const bf16x8 vf1 = *(const bf16x8*)(pV + rb + ((64 + lg * 16) ^ swzr));
      acc[dt] = MFMA_BF16(pa0, vf0, acc[dt]);
      acc[dt] = MFMA_BF16(pa1, vf1, acc[dt]);
    }
    acc_l = MFMA_BF16(pa0, ones, acc_l);
    acc_l = MFMA_BF16(pa1, ones, acc_l);
    __builtin_amdgcn_s_setprio(0);
    __syncthreads();     // drains vmcnt(0): next-step staging landed; dbuf safe
    cur ^= 1;
  }

  #pragma unroll
  for (int r = 0; r < 4; ++r) {
    const float rli = 1.0f / acc_l[r];          // rowsum for q = q0w+lg*4+r (in-lane)
    const size_t rowb = ((size_t)b * S_LEN + q0w + lg * 4 + r) * DIMSZ + h * HD;
    #pragma unroll
    for (int dt = 0; dt < 4; ++dt)
      attn[rowb + dt * 16 + lr] = __float2bfloat16(acc[dt][r] * rli);
  }

  // ---- fused weight casts on the 256 short blocks (qb<=7): exactly 10 f4/thread ----
  if ((rnd == 0) ? (u < 4) : (u >= 4)) {
    const int cid = (bh << 3) | u;          // 0..255, each (bh,u) once
    const int base = cid * 512 + tid;       // 0..131071
    #pragma unroll
    for (int i = 0; i < 10; ++i) {
      const int f = i * 131072 + base;      // f4 index into concat(wo[262144], wfc[524288], wpr[524288])
      const float* s; __hip_bfloat16* d; int off;
      if (f < 262144)      { s = wo_f;  d = wo_b;  off = f; }
      else if (f < 786432) { s = wfc_f; d = wfc_b; off = f - 262144; }
      else                 { s = wpr_f; d = wpr_b; off = f - 786432; }
      float4 v = ((const float4*)s)[off];
      __hip_bfloat16* o = d + (size_t)off * 4;
      o[0] = __float2bfloat16(v.x);
      o[1] = __float2bfloat16(v.y);
      o[2] = __float2bfloat16(v.z);
      o[3] = __float2bfloat16(v.w);
    }
  }
}

extern "C" void kernel_launch(void* const* d_in, const int* in_sizes, int n_in,
                              void* d_out, int out_size, void* d_ws, size_t ws_size,
                              hipStream_t stream)
{
  const float* x      = (const float*)d_in[0];
  const float* w_in   = (const float*)d_in[1];
  const float* w_ff   = (const float*)d_in[2];
  const float* w_qkv  = (const float*)d_in[3];
  const float* w_out  = (const float*)d_in[4];
  const float* w_fc   = (const float*)d_in[5];
  const float* w_proj = (const float*)d_in[6];
  float* out = (float*)d_out;
  char* ws = (char*)d_ws;

  __hip_bfloat16* wq_b   = (__hip_bfloat16*)(ws);               // 6,291,456
  __hip_bfloat16* wo_b   = (__hip_bfloat16*)(ws + 6291456);     // 2,097,152
  __hip_bfloat16* wfc_b  = (__hip_bfloat16*)(ws + 8388608);     // 4,194,304
  __hip_bfloat16* wpr_b  = (__hip_bfloat16*)(ws + 12582912);    // 4,194,304
  __hip_bfloat16* h_b    = (__hip_bfloat16*)(ws + 16777216);    // 8,388,608
  __hip_bfloat16* qkv_b  = (__hip_bfloat16*)(ws + 25165824);    // 25,165,824
  __hip_bfloat16* attn_b = (__hip_bfloat16*)(ws + 25165824);    // reuse qkv[0:8M]
  __hip_bfloat16* hid_b  = (__hip_bfloat16*)(ws + 33554432);    // reuse qkv[8M:24M]
  __hip_bfloat16* Q_b    = (__hip_bfloat16*)(ws + 50331648);    // 8,388,608
  __hip_bfloat16* K_b    = (__hip_bfloat16*)(ws + 58720256);    // 8,388,608
  __hip_bfloat16* Vt_b   = (__hip_bfloat16*)(ws + 67108864);    // 8,388,608
  __hip_bfloat16* x1b    = (__hip_bfloat16*)(ws + 50331648);    // bf16 residual, reuse Q after flash

  // 1. wq cast + pre-attn RMSNorm
  prep_kernel<<<3072 + 4096, 256, 0, stream>>>(w_qkv, wq_b, x, w_in, h_b);
  // 2. QKV GEMM  [BN=192: 512 blocks = one exact dispatch round]
  gemm_bt192<<<dim3(3072 / 192, 4096 / 128), 384, 0, stream>>>(h_b, wq_b, qkv_b, 3072, 1024);
  // 3. RoPE + V transpose (fused launch)
  rope_vt_kernel<<<8192 + 1024, 256, 0, stream>>>(qkv_b, Q_b, K_b, Vt_b);
  // 4. flash attention (+ wo/wfc/wpr casts on short blocks)
  flash_attn7<<<512, 512, 0, stream>>>(Q_b, K_b, Vt_b, attn_b,
                                       w_out, w_fc, w_proj, wo_b, wfc_b, wpr_b);
  // 5. out-proj + residual -> x1 (bf16)  [BM=64: 512 blocks, 3/CU]
  gemm_bt64<1><<<dim3(1024 / 128, 4096 / 64), 256, 0, stream>>>(attn_b, wo_b, nullptr, x1b, x, nullptr, 1024, 1024);
  // 6. pre-FF RMSNorm (bf16 in)
  rmsnorm_bf16_kernel<<<4096, 256, 0, stream>>>(x1b, w_ff, h_b);
  // 7. FC GEMM + SiLU
  gemm_bt2<2><<<dim3(2048 / 128, 4096 / 128), 256, 0, stream>>>(h_b, wfc_b, nullptr, hid_b, nullptr, nullptr, 2048, 1024);
  // 8. proj GEMM + bf16 residual -> out (fp32)  [BM=64: 512 blocks, 3/CU]
  gemm_bt64<3><<<dim3(1024 / 128, 4096 / 64), 256, 0, stream>>>(hid_b, wpr_b, out, nullptr, nullptr, x1b, 1024, 2048);
}

// Round 16
// 161.046 us; speedup vs baseline: 1.0157x; 1.0157x over previous
//
#include <hip/hip_runtime.h>
#include <hip/hip_bf16.h>
#include <cstdint>

#define DIMSZ 1024
#define S_LEN 2048
#define NH 16
#define HD 64

typedef __attribute__((ext_vector_type(4))) float f32x4;
typedef __attribute__((ext_vector_type(8))) __bf16 bf16x8;

#define MFMA_BF16(a,b,c) __builtin_amdgcn_mfma_f32_16x16x32_bf16((a),(b),(c),0,0,0)

__device__ __forceinline__ void gload_lds16(const void* g, void* l) {
  __builtin_amdgcn_global_load_lds(
      (const __attribute__((address_space(1))) unsigned int*)(uintptr_t)g,
      (__attribute__((address_space(3))) unsigned int*)(uintptr_t)l,
      16, 0, 0);
}

__device__ __forceinline__ float bf16bits2f(unsigned short u) {
  return __uint_as_float((unsigned)u << 16);
}

// single-op packed f32x2 -> bf16x2
__device__ __forceinline__ unsigned cvt_pk_bf16(float lo, float hi) {
  unsigned r;
  asm("v_cvt_pk_bf16_f32 %0, %1, %2" : "=v"(r) : "v"(lo), "v"(hi));
  return r;
}

// ---------------- prep: wq cast (blocks 0..3071) + pre-attn RMSNorm (3072..7167) ----
__global__ __launch_bounds__(256)
void prep_kernel(const float* __restrict__ wq_f, __hip_bfloat16* __restrict__ wq_b,
                 const float* __restrict__ x, const float* __restrict__ w_in,
                 __hip_bfloat16* __restrict__ h)
{
  __shared__ float red[4];
  const int bid = blockIdx.x;
  const int tid = threadIdx.x;
  if (bid < 3072) {
    int off = bid * 256 + tid;   // float4 index, total 786432
    float4 v = ((const float4*)wq_f)[off];
    __hip_bfloat16* o = wq_b + (size_t)off * 4;
    o[0] = __float2bfloat16(v.x);
    o[1] = __float2bfloat16(v.y);
    o[2] = __float2bfloat16(v.z);
    o[3] = __float2bfloat16(v.w);
    return;
  }
  const int row = bid - 3072;
  const float4 v = ((const float4*)(x + (size_t)row * DIMSZ))[tid];
  float ss = v.x*v.x + v.y*v.y + v.z*v.z + v.w*v.w;
  #pragma unroll
  for (int m = 32; m >= 1; m >>= 1) ss += __shfl_xor(ss, m);
  int wave = tid >> 6, lane = tid & 63;
  if (lane == 0) red[wave] = ss;
  __syncthreads();
  float tot = red[0] + red[1] + red[2] + red[3];
  float sc = rsqrtf(tot * (1.0f / DIMSZ) + 1e-6f);
  const float4 wv = ((const float4*)w_in)[tid];
  __hip_bfloat16* o = h + (size_t)row * DIMSZ + tid * 4;
  o[0] = __float2bfloat16(v.x * sc * wv.x);
  o[1] = __float2bfloat16(v.y * sc * wv.y);
  o[2] = __float2bfloat16(v.z * sc * wv.z);
  o[3] = __float2bfloat16(v.w * sc * wv.w);
}

// ---------------- RMSNorm over bf16 input (residual stream) -> bf16 out ----------------
__global__ __launch_bounds__(256)
void rmsnorm_bf16_kernel(const __hip_bfloat16* __restrict__ x, const float* __restrict__ w,
                         __hip_bfloat16* __restrict__ out)
{
  int row = blockIdx.x;
  int tid = threadIdx.x;
  const ushort4 raw = ((const ushort4*)(x + (size_t)row * DIMSZ))[tid];
  float v0 = bf16bits2f(raw.x), v1 = bf16bits2f(raw.y);
  float v2 = bf16bits2f(raw.z), v3 = bf16bits2f(raw.w);
  float ss = v0*v0 + v1*v1 + v2*v2 + v3*v3;
  #pragma unroll
  for (int m = 32; m >= 1; m >>= 1) ss += __shfl_xor(ss, m);
  __shared__ float red[4];
  int wave = tid >> 6, lane = tid & 63;
  if (lane == 0) red[wave] = ss;
  __syncthreads();
  float tot = red[0] + red[1] + red[2] + red[3];
  float sc = rsqrtf(tot * (1.0f / DIMSZ) + 1e-6f);
  const float4 wv = ((const float4*)w)[tid];
  __hip_bfloat16* o = out + (size_t)row * DIMSZ + tid * 4;
  o[0] = __float2bfloat16(v0 * sc * wv.x);
  o[1] = __float2bfloat16(v1 * sc * wv.y);
  o[2] = __float2bfloat16(v2 * sc * wv.z);
  o[3] = __float2bfloat16(v3 * sc * wv.w);
}

// ---------------- GEMM v2: 128x128 2-phase, BK=64, dbuf, swizzled (verified) ---
// EPI 0: bf16 raw; EPI 1: bf16(residf + acc); EPI 2: bf16 silu(acc);
// EPI 3: fp32 (residb + acc).
template<int EPI>
__global__ __launch_bounds__(256, 2)
void gemm_bt2(const __hip_bfloat16* __restrict__ A,
              const __hip_bfloat16* __restrict__ Bw,
              float* __restrict__ Cf,
              __hip_bfloat16* __restrict__ Cb,
              const float* __restrict__ residf,
              const __hip_bfloat16* __restrict__ residb,
              int N, int K)
{
  __shared__ __align__(16) char sA[2][16384];   // [128 rows][128 B]
  __shared__ __align__(16) char sB[2][16384];
  const int tid = threadIdx.x;
  const int wave = tid >> 6, lane = tid & 63;
  const int lg = lane >> 4, lr15 = lane & 15;
  const int row0 = blockIdx.y * 128, col0 = blockIdx.x * 128;
  const int wr = wave >> 1, wc = wave & 1;
  f32x4 acc[4][4] = {};

  const size_t Kb = (size_t)K * 2;
  const int rown = tid >> 3;               // 0..31
  const int scol = ((tid & 7) << 4) ^ ((rown & 7) << 4);
  const char* gA = (const char*)A + (size_t)(row0 + rown) * Kb + scol;
  const char* gB = (const char*)Bw + (size_t)(col0 + rown) * Kb + scol;
  const int dbase = wave * 1024;

  const int nsteps = K >> 6;
  int cur = 0;

#define STAGE_G(buf, st) do {                                              \
    const size_t kb_ = (size_t)(st) * 128;                                 \
    _Pragma("unroll")                                                      \
    for (int it = 0; it < 4; ++it) {                                       \
      gload_lds16(gA + (size_t)(it * 32) * Kb + kb_, &sA[buf][it * 4096 + dbase]); \
      gload_lds16(gB + (size_t)(it * 32) * Kb + kb_, &sB[buf][it * 4096 + dbase]); \
    }                                                                      \
  } while (0)

  STAGE_G(0, 0);
  __syncthreads();

  const int swz = (lr15 & 7) << 4;
  for (int st = 0; st < nsteps; ++st) {
    if (st + 1 < nsteps) STAGE_G(cur ^ 1, st + 1);
    const char* pA = sA[cur];
    const char* pB = sB[cur];
    bf16x8 af[2][4], bfr[2][4];
    #pragma unroll
    for (int m = 0; m < 4; ++m) {
      const int ra = (wr * 64 + m * 16 + lr15) * 128;
      af[0][m] = *(const bf16x8*)(pA + ra + ((lg * 16) ^ swz));
      af[1][m] = *(const bf16x8*)(pA + ra + ((64 + lg * 16) ^ swz));
      const int rb = (wc * 64 + m * 16 + lr15) * 128;
      bfr[0][m] = *(const bf16x8*)(pB + rb + ((lg * 16) ^ swz));
      bfr[1][m] = *(const bf16x8*)(pB + rb + ((64 + lg * 16) ^ swz));
    }
    #pragma unroll
    for (int kh = 0; kh < 2; ++kh)
      #pragma unroll
      for (int m = 0; m < 4; ++m)
        #pragma unroll
        for (int n = 0; n < 4; ++n)
          acc[m][n] = MFMA_BF16(af[kh][m], bfr[kh][n], acc[m][n]);
    __syncthreads();
    cur ^= 1;
  }
#undef STAGE_G

  #pragma unroll
  for (int m = 0; m < 4; ++m) {
    #pragma unroll
    for (int n = 0; n < 4; ++n) {
      #pragma unroll
      for (int r = 0; r < 4; ++r) {
        const int grow = row0 + wr * 64 + m * 16 + lg * 4 + r;
        const int gcol = col0 + wc * 64 + n * 16 + lr15;
        const size_t idx = (size_t)grow * N + gcol;
        const float v = acc[m][n][r];
        if (EPI == 0) {
          Cb[idx] = __float2bfloat16(v);
        } else if (EPI == 1) {
          Cb[idx] = __float2bfloat16(residf[idx] + v);
        } else if (EPI == 2) {
          Cb[idx] = __float2bfloat16(v / (1.0f + __expf(-v)));
        } else {
          Cf[idx] = __bfloat162float(residb[idx]) + v;
        }
      }
    }
  }
}

// ---------------- GEMM BM=64: 64x128 tile, 2-phase, 48 KB LDS, 3 blocks/CU ----------
template<int EPI>
__global__ __launch_bounds__(256, 3)
void gemm_bt64(const __hip_bfloat16* __restrict__ A,
               const __hip_bfloat16* __restrict__ Bw,
               float* __restrict__ Cf,
               __hip_bfloat16* __restrict__ Cb,
               const float* __restrict__ residf,
               const __hip_bfloat16* __restrict__ residb,
               int N, int K)
{
  __shared__ __align__(16) char sA[2][8192];    // [64 rows][128 B]
  __shared__ __align__(16) char sB[2][16384];   // [128 rows][128 B]
  const int tid = threadIdx.x;
  const int wave = tid >> 6, lane = tid & 63;
  const int lg = lane >> 4, lr15 = lane & 15;
  const int row0 = blockIdx.y * 64, col0 = blockIdx.x * 128;
  const int wr = wave >> 1, wc = wave & 1;
  f32x4 acc[2][4] = {};

  const size_t Kb = (size_t)K * 2;
  const int rown = tid >> 3;               // 0..31
  const int scol = ((tid & 7) << 4) ^ ((rown & 7) << 4);
  const char* gA = (const char*)A + (size_t)(row0 + rown) * Kb + scol;
  const char* gB = (const char*)Bw + (size_t)(col0 + rown) * Kb + scol;
  const int dbase = wave * 1024;

  const int nsteps = K >> 6;
  int cur = 0;

#define STAGE_G64(buf, st) do {                                            \
    const size_t kb_ = (size_t)(st) * 128;                                 \
    _Pragma("unroll")                                                      \
    for (int it = 0; it < 2; ++it)                                         \
      gload_lds16(gA + (size_t)(it * 32) * Kb + kb_, &sA[buf][it * 4096 + dbase]); \
    _Pragma("unroll")                                                      \
    for (int it = 0; it < 4; ++it)                                         \
      gload_lds16(gB + (size_t)(it * 32) * Kb + kb_, &sB[buf][it * 4096 + dbase]); \
  } while (0)

  STAGE_G64(0, 0);
  __syncthreads();

  const int swz = (lr15 & 7) << 4;
  for (int st = 0; st < nsteps; ++st) {
    if (st + 1 < nsteps) STAGE_G64(cur ^ 1, st + 1);
    const char* pA = sA[cur];
    const char* pB = sB[cur];
    bf16x8 af[2][2], bfr[2][4];
    #pragma unroll
    for (int m = 0; m < 2; ++m) {
      const int ra = (wr * 32 + m * 16 + lr15) * 128;
      af[0][m] = *(const bf16x8*)(pA + ra + ((lg * 16) ^ swz));
      af[1][m] = *(const bf16x8*)(pA + ra + ((64 + lg * 16) ^ swz));
    }
    #pragma unroll
    for (int n = 0; n < 4; ++n) {
      const int rb = (wc * 64 + n * 16 + lr15) * 128;
      bfr[0][n] = *(const bf16x8*)(pB + rb + ((lg * 16) ^ swz));
      bfr[1][n] = *(const bf16x8*)(pB + rb + ((64 + lg * 16) ^ swz));
    }
    #pragma unroll
    for (int kh = 0; kh < 2; ++kh)
      #pragma unroll
      for (int m = 0; m < 2; ++m)
        #pragma unroll
        for (int n = 0; n < 4; ++n)
          acc[m][n] = MFMA_BF16(af[kh][m], bfr[kh][n], acc[m][n]);
    __syncthreads();
    cur ^= 1;
  }
#undef STAGE_G64

  #pragma unroll
  for (int m = 0; m < 2; ++m) {
    #pragma unroll
    for (int n = 0; n < 4; ++n) {
      #pragma unroll
      for (int r = 0; r < 4; ++r) {
        const int grow = row0 + wr * 32 + m * 16 + lg * 4 + r;
        const int gcol = col0 + wc * 64 + n * 16 + lr15;
        const size_t idx = (size_t)grow * N + gcol;
        const float v = acc[m][n][r];
        if (EPI == 1) {
          Cb[idx] = __float2bfloat16(residf[idx] + v);
        } else {
          Cf[idx] = __bfloat162float(residb[idx]) + v;
        }
      }
    }
  }
}

// ---------------- fused RoPE (blocks 0..8191) + V transpose (8192..9215) ----------
__global__ __launch_bounds__(256)
void rope_vt_kernel(const __hip_bfloat16* __restrict__ qkv,
                    __hip_bfloat16* __restrict__ Q, __hip_bfloat16* __restrict__ Kx,
                    __hip_bfloat16* __restrict__ Vt)
{
  __shared__ __hip_bfloat16 t[64][72];
  const int bid = blockIdx.x;
  const int tid = threadIdx.x;
  if (bid < 8192) {
    int idx = bid * 256 + tid;   // bits: i:5, h:4, s:11, b:1
    int i = idx & 31;
    int h = (idx >> 5) & 15;
    int s = (idx >> 9) & (S_LEN - 1);
    int b = idx >> 20;
    const size_t base = ((size_t)b * S_LEN + s) * 3072 + h * 64 + 2 * i;
    float qe = __bfloat162float(qkv[base]);
    float qo = __bfloat162float(qkv[base + 1]);
    float ke = __bfloat162float(qkv[base + 1024]);
    float ko = __bfloat162float(qkv[base + 1025]);
    float inv = __expf(-(2.0f * i) * (9.210340371976184f / 64.0f));
    float ang = (float)s * inv;
    float sn, cs;
    __sincosf(ang, &sn, &cs);
    const float sc = 0.125f;   // 1/sqrt(HD) folded into Q
    size_t qb = (((size_t)b * NH + h) * S_LEN + s) * HD + 2 * i;
    Q[qb]     = __float2bfloat16((qe * cs - qo * sn) * sc);
    Q[qb + 1] = __float2bfloat16((qo * cs + qe * sn) * sc);
    Kx[qb]     = __float2bfloat16(ke * cs - ko * sn);
    Kx[qb + 1] = __float2bfloat16(ko * cs + ke * sn);
    return;
  }
  const int v = bid - 8192;          // 0..1023
  const int bh = v >> 5;
  const int s0 = (v & 31) * 64;
  const int b = bh >> 4, h = bh & 15;
  const int c = tid & 63;
  #pragma unroll
  for (int r = 0; r < 16; ++r) {
    int srow = r * 4 + (tid >> 6);
    t[srow][c] = qkv[((size_t)b * S_LEN + s0 + srow) * 3072 + 2048 + h * 64 + c];
  }
  __syncthreads();
  #pragma unroll
  for (int r = 0; r < 16; ++r) {
    int drow = r * 4 + (tid >> 6);
    Vt[(((size_t)b * NH + h) * HD + drow) * S_LEN + s0 + c] = t[c][drow];
  }
}

// ---------------- flash attention v7 (round-10 verified, 42.3 us) ----------------
__global__ __launch_bounds__(512, 4)
void flash_attn7(const __hip_bfloat16* __restrict__ Q,
                 const __hip_bfloat16* __restrict__ Kx,
                 const __hip_bfloat16* __restrict__ Vt,
                 __hip_bfloat16* __restrict__ attn,
                 const float* __restrict__ wo_f, const float* __restrict__ wfc_f,
                 const float* __restrict__ wpr_f,
                 __hip_bfloat16* __restrict__ wo_b, __hip_bfloat16* __restrict__ wfc_b,
                 __hip_bfloat16* __restrict__ wpr_b)
{
  __shared__ __align__(16) char sK[2][8192];
  __shared__ __align__(16) char sV[2][8192];
  __shared__ __align__(16) char sP[8][2048];

  const int tid = threadIdx.x;
  const int w = tid >> 6;           // wave 0..7
  const int lane = tid & 63;
  const int lg = lane >> 4, lr = lane & 15;
  const int bid = blockIdx.x;
  const int bh = bid & 31;          // b*16+h
  const int b = bh >> 4, h = bh & 15;
  const int u = (bid >> 5) & 7;     // slot within dispatch round
  const int rnd = bid >> 8;         // 0 or 1
  const int qb = rnd == 0 ? (u << 1) : (15 - (u << 1));   // {0,2,..14} then {15,13,..1}
  const int q0 = qb << 7;           // *128
  const int nsteps = (qb << 1) + 2;

  const char* Kb = (const char*)(Kx + (size_t)bh * S_LEN * HD);   // [S][64] bf16
  const char* Vb = (const char*)(Vt + (size_t)bh * HD * S_LEN);   // [64][S] bf16
  const __hip_bfloat16* Qp = Q + (size_t)bh * S_LEN * HD;

  const int q0w = q0 + w * 16;
  const bf16x8 qf0 = *(const bf16x8*)&Qp[(q0w + lr) * HD + lg * 8];
  const bf16x8 qf1 = *(const bf16x8*)&Qp[(q0w + lr) * HD + 32 + lg * 8];
  char* sPw = sP[w];
  const int swzr = (lr & 7) << 4;
  const int srow = tid >> 3;
  const int scol = ((tid & 7) << 4) ^ ((srow & 7) << 4);
  const int wbase = w << 10;        // wave-uniform LDS chunk

  bf16x8 ones;
  #pragma unroll
  for (int i = 0; i < 8; ++i) ones[i] = (__bf16)1.0f;

  f32x4 acc[4] = {};
  f32x4 acc_l = {};                 // rowsum of P (denominator)
  int cur = 0;

  gload_lds16(Kb + (size_t)srow * 128 + scol, sK[0] + wbase);
  gload_lds16(Vb + (size_t)srow * (S_LEN * 2) + scol, sV[0] + wbase);
  __syncthreads();

  for (int st = 0; st < nsteps; ++st) {
    if (st + 1 < nsteps) {
      const size_t kn = (size_t)(st + 1) * 64;
      gload_lds16(Kb + (kn + srow) * 128 + scol, sK[cur ^ 1] + wbase);
      gload_lds16(Vb + (size_t)srow * (S_LEN * 2) + kn * 2 + scol, sV[cur ^ 1] + wbase);
    }
    const int k0 = st * 64;
    const char* pK = sK[cur];
    const char* pV = sV[cur];
    f32x4 sv[4];
    __builtin_amdgcn_s_setprio(1);
    #pragma unroll
    for (int t = 0; t < 4; ++t) {
      const int rb = (t * 16 + lr) * 128;
      const bf16x8 kf0 = *(const bf16x8*)(pK + rb + ((lg * 16) ^ swzr));
      const bf16x8 kf1 = *(const bf16x8*)(pK + rb + ((64 + lg * 16) ^ swzr));
      f32x4 z = {};
      z = MFMA_BF16(kf0, qf0, z);
      z = MFMA_BF16(kf1, qf1, z);
      sv[t] = z;
    }
    __builtin_amdgcn_s_setprio(0);
    const bool maskstep = (st >= nsteps - 2);   // last two steps cross the diagonal
    #pragma unroll
    for (int t = 0; t < 4; ++t) {
      float p[4];
      #pragma unroll
      for (int r = 0; r < 4; ++r) {
        float e = __expf(sv[t][r]);
        if (maskstep) {
          const int kg = k0 + t * 16 + lg * 4 + r;
          e = (kg <= q0w + lr) ? e : 0.f;
        }
        p[r] = e;
      }
      uint2 wv2;
      wv2.x = cvt_pk_bf16(p[0], p[1]);
      wv2.y = cvt_pk_bf16(p[2], p[3]);
      *(uint2*)(sPw + lr * 128 + ((t * 32 + lg * 8) ^ swzr)) = wv2;
    }
    asm volatile("s_waitcnt lgkmcnt(0)" ::: "memory");
    __builtin_amdgcn_sched_barrier(0);
    const bf16x8 pa0 = *(const bf16x8*)(sPw + lr * 128 + ((lg * 16) ^ swzr));
    const bf16x8 pa1 = *(const bf16x8*)(sPw + lr * 128 + ((64 + lg * 16) ^ swzr));
    __builtin_amdgcn_s_setprio(1);
    #pragma unroll
    for (int dt = 0; dt < 4; ++dt) {
      const int rb = (dt * 16 + lr) * 128;
      const bf16x8 vf0 = *(const bf16x8*)(pV + rb + ((lg * 16) ^ swzr));
      const bf16x8 vf1 = *(const bf16x8*)(pV + rb + ((64 + lg * 16) ^ swzr));
      acc[dt] = MFMA_BF16(pa0, vf0, acc[dt]);
      acc[dt] = MFMA_BF16(pa1, vf1, acc[dt]);
    }
    acc_l = MFMA_BF16(pa0, ones, acc_l);
    acc_l = MFMA_BF16(pa1, ones, acc_l);
    __builtin_amdgcn_s_setprio(0);
    __syncthreads();     // drains vmcnt(0): next-step staging landed; dbuf safe
    cur ^= 1;
  }

  #pragma unroll
  for (int r = 0; r < 4; ++r) {
    const float rli = 1.0f / acc_l[r];          // rowsum for q = q0w+lg*4+r (in-lane)
    const size_t rowb = ((size_t)b * S_LEN + q0w + lg * 4 + r) * DIMSZ + h * HD;
    #pragma unroll
    for (int dt = 0; dt < 4; ++dt)
      attn[rowb + dt * 16 + lr] = __float2bfloat16(acc[dt][r] * rli);
  }

  // ---- fused weight casts on the 256 short blocks (qb<=7): exactly 10 f4/thread ----
  if ((rnd == 0) ? (u < 4) : (u >= 4)) {
    const int cid = (bh << 3) | u;          // 0..255, each (bh,u) once
    const int base = cid * 512 + tid;       // 0..131071
    #pragma unroll
    for (int i = 0; i < 10; ++i) {
      const int f = i * 131072 + base;      // f4 index into concat(wo[262144], wfc[524288], wpr[524288])
      const float* s; __hip_bfloat16* d; int off;
      if (f < 262144)      { s = wo_f;  d = wo_b;  off = f; }
      else if (f < 786432) { s = wfc_f; d = wfc_b; off = f - 262144; }
      else                 { s = wpr_f; d = wpr_b; off = f - 786432; }
      float4 v = ((const float4*)s)[off];
      __hip_bfloat16* o = d + (size_t)off * 4;
      o[0] = __float2bfloat16(v.x);
      o[1] = __float2bfloat16(v.y);
      o[2] = __float2bfloat16(v.z);
      o[3] = __float2bfloat16(v.w);
    }
  }
}

extern "C" void kernel_launch(void* const* d_in, const int* in_sizes, int n_in,
                              void* d_out, int out_size, void* d_ws, size_t ws_size,
                              hipStream_t stream)
{
  const float* x      = (const float*)d_in[0];
  const float* w_in   = (const float*)d_in[1];
  const float* w_ff   = (const float*)d_in[2];
  const float* w_qkv  = (const float*)d_in[3];
  const float* w_out  = (const float*)d_in[4];
  const float* w_fc   = (const float*)d_in[5];
  const float* w_proj = (const float*)d_in[6];
  float* out = (float*)d_out;
  char* ws = (char*)d_ws;

  __hip_bfloat16* wq_b   = (__hip_bfloat16*)(ws);               // 6,291,456
  __hip_bfloat16* wo_b   = (__hip_bfloat16*)(ws + 6291456);     // 2,097,152
  __hip_bfloat16* wfc_b  = (__hip_bfloat16*)(ws + 8388608);     // 4,194,304
  __hip_bfloat16* wpr_b  = (__hip_bfloat16*)(ws + 12582912);    // 4,194,304
  __hip_bfloat16* h_b    = (__hip_bfloat16*)(ws + 16777216);    // 8,388,608
  __hip_bfloat16* qkv_b  = (__hip_bfloat16*)(ws + 25165824);    // 25,165,824
  __hip_bfloat16* attn_b = (__hip_bfloat16*)(ws + 25165824);    // reuse qkv[0:8M]
  __hip_bfloat16* hid_b  = (__hip_bfloat16*)(ws + 33554432);    // reuse qkv[8M:24M]
  __hip_bfloat16* Q_b    = (__hip_bfloat16*)(ws + 50331648);    // 8,388,608
  __hip_bfloat16* K_b    = (__hip_bfloat16*)(ws + 58720256);    // 8,388,608
  __hip_bfloat16* Vt_b   = (__hip_bfloat16*)(ws + 67108864);    // 8,388,608
  __hip_bfloat16* x1b    = (__hip_bfloat16*)(ws + 50331648);    // bf16 residual, reuse Q after flash

  // 1. wq cast + pre-attn RMSNorm
  prep_kernel<<<3072 + 4096, 256, 0, stream>>>(w_qkv, wq_b, x, w_in, h_b);
  // 2. QKV GEMM
  gemm_bt2<0><<<dim3(3072 / 128, 4096 / 128), 256, 0, stream>>>(h_b, wq_b, nullptr, qkv_b, nullptr, nullptr, 3072, 1024);
  // 3. RoPE + V transpose (fused launch)
  rope_vt_kernel<<<8192 + 1024, 256, 0, stream>>>(qkv_b, Q_b, K_b, Vt_b);
  // 4. flash attention (+ wo/wfc/wpr casts on short blocks)
  flash_attn7<<<512, 512, 0, stream>>>(Q_b, K_b, Vt_b, attn_b,
                                       w_out, w_fc, w_proj, wo_b, wfc_b, wpr_b);
  // 5. out-proj + residual -> x1 (bf16)  [BM=64: 512 blocks, 3/CU]
  gemm_bt64<1><<<dim3(1024 / 128, 4096 / 64), 256, 0, stream>>>(attn_b, wo_b, nullptr, x1b, x, nullptr, 1024, 1024);
  // 6. pre-FF RMSNorm (bf16 in)
  rmsnorm_bf16_kernel<<<4096, 256, 0, stream>>>(x1b, w_ff, h_b);
  // 7. FC GEMM + SiLU
  gemm_bt2<2><<<dim3(2048 / 128, 4096 / 128), 256, 0, stream>>>(h_b, wfc_b, nullptr, hid_b, nullptr, nullptr, 2048, 1024);
  // 8. proj GEMM + bf16 residual -> out (fp32)  [BM=64: 512 blocks, 3/CU]
  gemm_bt64<3><<<dim3(1024 / 128, 4096 / 64), 256, 0, stream>>>(hid_b, wpr_b, out, nullptr, nullptr, x1b, 1024, 2048);
}